// Round 3
// baseline (368.756 us; speedup 1.0000x reference)
//
#include <hip/hip_runtime.h>
#include <stdint.h>

#define NB 32
#define CC 64
#define HH 112
#define WW 112
#define HW (HH * WW)            // 12544
#define NHW (NB * HW)           // 401408
#define ROWS (NB * HH)          // 3584
#define XP_BLOCKS (NHW / 4 / 256) // 392, exact

__device__ __forceinline__ void wave_fence() {
    // compiler memory fence + scheduling barrier; LDS is in-order per wave,
    // so intra-wave LDS RAW/WAR needs no s_barrier and no explicit waitcnt.
    asm volatile("" ::: "memory");
    __builtin_amdgcn_wave_barrier();
}

// ---------------- kernel 1: binarize weights -> bits + scale; zero stat accumulators
__global__ void wpack_kernel(const float* __restrict__ wflat,
                             uint64_t* __restrict__ wbits,
                             float* __restrict__ wscale,
                             int* __restrict__ ch_sum,
                             unsigned long long* __restrict__ ch_sumsq) {
    int o = blockIdx.x;      // 64 blocks, one per output channel
    int i = threadIdx.x;     // 64 threads = input channel (lane id)
    const float* wp = wflat + (size_t)(o * 64 + i) * 9;
    float w[9];
    float asum = 0.f;
#pragma unroll
    for (int t = 0; t < 9; t++) { w[t] = wp[t]; asum += fabsf(w[t]); }
#pragma unroll
    for (int s = 32; s > 0; s >>= 1) asum += __shfl_xor(asum, s, 64);
    float scale = asum * (1.0f / 576.0f);
    uint64_t b[9];
#pragma unroll
    for (int t = 0; t < 9; t++) b[t] = __ballot(w[t] >= 0.0f);  // bit i = sign(+) of in-channel i
    if (i == 0) {
#pragma unroll
        for (int t = 0; t < 9; t++) wbits[o * 9 + t] = b[t];
        wscale[o] = scale;
        ch_sum[o] = 0;
        ch_sumsq[o] = 0ull;
    }
}

// ---------------- kernel 2: pack sign(x) bits, 4 pixels/thread via float4
__global__ __launch_bounds__(256) void xpack4_kernel(const float* __restrict__ x,
                                                     uint64_t* __restrict__ bits) {
    int q = blockIdx.x * 256 + threadIdx.x;   // q < NHW/4 exactly
    int p = q * 4;
    int n = p / HW;
    int r = p - n * HW;                        // multiple of 4, HW%4==0 so no image straddle
    const float* xp = x + (size_t)n * CC * HW + r;
    uint64_t b0 = 0, b1 = 0, b2 = 0, b3 = 0;
#pragma unroll
    for (int c = 0; c < 64; c++) {
        float4 v = *(const float4*)(xp + (size_t)c * HW);
        b0 |= (uint64_t)(v.x > 0.0f) << c;
        b1 |= (uint64_t)(v.y > 0.0f) << c;
        b2 |= (uint64_t)(v.z > 0.0f) << c;
        b3 |= (uint64_t)(v.w > 0.0f) << c;
    }
    ulonglong2* bp = (ulonglong2*)(bits + p);
    bp[0] = make_ulonglong2(b0, b1);
    bp[1] = make_ulonglong2(b2, b3);
}

// ---- shared helpers for the row-wave (lane=channel) conv structure ----

// stage 3 zero-padded bit rows (114 cols) for this wave's row into LDS
__device__ __forceinline__ void stage_rows(uint64_t (*rb)[114], const uint64_t* __restrict__ bp,
                                           int h, int lane) {
    for (int e = lane; e < 3 * 114; e += 64) {
        int t = e / 114, c = e - t * 114;
        int hh = h - 1 + t;
        uint64_t v = 0;
        if (c >= 1 && c <= 112 && hh >= 0 && hh < HH) v = bp[hh * WW + (c - 1)];
        rb[t][c] = v;
    }
}

// per-lane weight regs + boundary corrections
struct WRegs {
    uint64_t w[9];
    int corrMid, dL, dR;
};

__device__ __forceinline__ void load_wregs(WRegs& W, const uint64_t* __restrict__ wbits,
                                           int lane, int h) {
    int tc[9];
#pragma unroll
    for (int t = 0; t < 9; t++) {
        W.w[t] = wbits[lane * 9 + t];
        tc[t] = 64 - 2 * (int)__builtin_popcountll(W.w[t]);
    }
    W.corrMid = 0;
    int oL = 0, oR = 0;
    if (h == 0)      { W.corrMid = tc[0] + tc[1] + tc[2]; oL = tc[0]; oR = tc[2]; }
    if (h == HH - 1) { W.corrMid = tc[6] + tc[7] + tc[8]; oL = tc[6]; oR = tc[8]; }
    W.dL = tc[0] + tc[3] + tc[6] - oL;
    W.dR = tc[2] + tc[5] + tc[8] - oR;
}

// compute S for pixel with window cols (l,m,r), each col = 3 rows of u64
__device__ __forceinline__ int conv_px(const uint64_t l[3], const uint64_t m[3],
                                       const uint64_t r[3], const WRegs& W) {
    int pc = 0;
#pragma unroll
    for (int rr = 0; rr < 3; rr++) {
        pc += (int)__builtin_popcountll(l[rr] ^ W.w[rr * 3 + 0]);
        pc += (int)__builtin_popcountll(m[rr] ^ W.w[rr * 3 + 1]);
        pc += (int)__builtin_popcountll(r[rr] ^ W.w[rr * 3 + 2]);
    }
    return 576 - 2 * pc - W.corrMid;
}

// ---------------- kernel 3: conv + per-channel sum / sumsq (integer exact)
// ONE wave per block, wave = one image row, lane = output channel. No barriers.
__global__ __launch_bounds__(64) void stats3_kernel(const uint64_t* __restrict__ bits,
                                                    const uint64_t* __restrict__ wbits,
                                                    int* __restrict__ ch_sum,
                                                    unsigned long long* __restrict__ ch_sumsq) {
    __shared__ uint64_t rb[3][114];
    int lane = threadIdx.x;
    int rowIdx = blockIdx.x;                 // < ROWS exact
    int n = rowIdx / HH, h = rowIdx - n * HH;
    const uint64_t* bp = bits + (size_t)n * HW;

    stage_rows(rb, bp, h, lane);
    WRegs W;
    load_wregs(W, wbits, lane, h);
    wave_fence();

    int s1 = 0, s2 = 0;
    uint64_t win[3][3];
    for (int c0 = 0; c0 < WW; c0 += 16) {
#pragma unroll
        for (int rr = 0; rr < 3; rr++) { win[0][rr] = rb[rr][c0]; win[1][rr] = rb[rr][c0 + 1]; }
#pragma unroll
        for (int j = 0; j < 16; j++) {
#pragma unroll
            for (int rr = 0; rr < 3; rr++) win[(j + 2) % 3][rr] = rb[rr][c0 + j + 2];
            int S = conv_px(win[j % 3], win[(j + 1) % 3], win[(j + 2) % 3], W);
            int w = c0 + j;
            if (w == 0) S -= W.dL;
            if (w == WW - 1) S -= W.dR;
            s1 += S;
            s2 += S * S;
        }
    }
    atomicAdd(&ch_sum[lane], s1);
    atomicAdd(&ch_sumsq[lane], (unsigned long long)(long long)s2);
}

// ---------------- kernel 4: fold BN stats into per-channel affine a,b
__global__ void bnprep_kernel(const int* __restrict__ ch_sum,
                              const unsigned long long* __restrict__ ch_sumsq,
                              const float* __restrict__ wscale,
                              const float* __restrict__ gamma,
                              const float* __restrict__ beta,
                              float* __restrict__ aC, float* __restrict__ bC) {
    int o = threadIdx.x;  // 64 threads
    double P = (double)NHW;
    double meanS = (double)ch_sum[o] / P;
    double e2 = (double)ch_sumsq[o] / P;
    double varS = e2 - meanS * meanS;
    double sc = (double)wscale[o];
    double mean_y = sc * meanS;
    double var_y = sc * sc * varS;
    double inv = (double)gamma[o] / sqrt(var_y + 1e-5);
    aC[o] = (float)(sc * inv);
    bC[o] = (float)((double)beta[o] - mean_y * inv);
}

// ---------------- kernel 5: conv + BN affine + residual. ONE wave per block,
// intra-wave LDS transpose (conflict-free), no block barriers.
__global__ __launch_bounds__(64) void final3_kernel(const uint64_t* __restrict__ bits,
                                                    const uint64_t* __restrict__ wbits,
                                                    const float* __restrict__ aC,
                                                    const float* __restrict__ bC,
                                                    const float* __restrict__ x,
                                                    float* __restrict__ out) {
    __shared__ uint64_t rb[3][114];
    __shared__ float tile[64][17];   // [channel][pixel-in-chunk], +1 pad
    int lane = threadIdx.x;
    int rowIdx = blockIdx.x;
    int n = rowIdx / HH, h = rowIdx - n * HH;
    const uint64_t* bp = bits + (size_t)n * HW;

    stage_rows(rb, bp, h, lane);
    WRegs W;
    load_wregs(W, wbits, lane, h);
    float a = aC[lane], b = bC[lane];
    wave_fence();

    // transpose read mapping: cg=lane&3, wi=lane>>2, ch=cg*16+k
    // LDS bank = ((cg&1)*16 + wi + 17k) % 32 -> exactly 2 lanes/bank (free)
    int cg = lane & 3, wi = lane >> 2;
    size_t rowbase = (size_t)n * CC * HW + (size_t)h * WW;
    uint64_t win[3][3];
    for (int c0 = 0; c0 < WW; c0 += 16) {
#pragma unroll
        for (int rr = 0; rr < 3; rr++) { win[0][rr] = rb[rr][c0]; win[1][rr] = rb[rr][c0 + 1]; }
#pragma unroll
        for (int j = 0; j < 16; j++) {
#pragma unroll
            for (int rr = 0; rr < 3; rr++) win[(j + 2) % 3][rr] = rb[rr][c0 + j + 2];
            int S = conv_px(win[j % 3], win[(j + 1) % 3], win[(j + 2) % 3], W);
            int w = c0 + j;
            if (w == 0) S -= W.dL;
            if (w == WW - 1) S -= W.dR;
            tile[lane][j] = (float)S * a + b;
        }
        wave_fence();
#pragma unroll
        for (int k = 0; k < 16; k++) {
            int ch = cg * 16 + k;
            float y = tile[ch][wi];
            size_t off = rowbase + (size_t)ch * HW + c0 + wi;
            out[off] = y + x[off];
        }
        wave_fence();
    }
}

extern "C" void kernel_launch(void* const* d_in, const int* in_sizes, int n_in,
                              void* d_out, int out_size, void* d_ws, size_t ws_size,
                              hipStream_t stream) {
    const float* x     = (const float*)d_in[0];
    const float* wflat = (const float*)d_in[1];
    const float* gamma = (const float*)d_in[2];
    const float* beta  = (const float*)d_in[3];
    float* out = (float*)d_out;

    char* ws = (char*)d_ws;
    uint64_t* bits  = (uint64_t*)ws;                          // 401408*8 = 3,211,264 B
    uint64_t* wbits = (uint64_t*)(ws + 3211264);              // 576*8 = 4608 B
    float* wscale   = (float*)(ws + 3215872);                 // 256 B
    int* ch_sum     = (int*)(ws + 3216128);                   // 256 B
    unsigned long long* ch_sumsq = (unsigned long long*)(ws + 3216384); // 512 B
    float* aC       = (float*)(ws + 3216896);                 // 256 B
    float* bC       = (float*)(ws + 3217152);                 // 256 B

    wpack_kernel<<<64, 64, 0, stream>>>(wflat, wbits, wscale, ch_sum, ch_sumsq);
    xpack4_kernel<<<XP_BLOCKS, 256, 0, stream>>>(x, bits);
    stats3_kernel<<<ROWS, 64, 0, stream>>>(bits, wbits, ch_sum, ch_sumsq);
    bnprep_kernel<<<1, 64, 0, stream>>>(ch_sum, ch_sumsq, wscale, gamma, beta, aC, bC);
    final3_kernel<<<ROWS, 64, 0, stream>>>(bits, wbits, aC, bC, x, out);
}